// Round 6
// baseline (3899.950 us; speedup 1.0000x reference)
//
#include <hip/hip_runtime.h>
#include <hip/hip_bf16.h>
#include <math.h>

// ---------------------------------------------------------------------------
// PointNet++ Set Abstraction: FPS -> kNN -> grouped MLP(6->32->32->64) with
// BatchNorm(training stats) + ReLU -> max over K.
// B=8, N=8192, S=2048, K=32. All fp32.
//
// R5 structure: mega-kernel pipelines kNN + stage0-stats BEHIND fps.
// fps blocks (0..7, 8 CUs) publish centroid progress per 64-iter tile;
// knn blocks (8..263, on the other 248 CUs) acquire-spin per tile, so all
// knn + gather + stage0 work is hidden under fps's ~2ms serial latency.
//
// d_out layout (floats): new_xyz [8,3,2048] | new_points [8,64,2048] | fps_idx [8,2048]
// ---------------------------------------------------------------------------

#define NB 8
#define NN 8192
#define NS 2048
#define NK 32

// ---------------- prep: transpose to [B,N,4] with w = |p|^2 -----------------
__global__ __launch_bounds__(256) void prep_kernel(const float* __restrict__ xyz,
                                                   const float* __restrict__ pts,
                                                   float4* __restrict__ xyz4,
                                                   float4* __restrict__ pts4,
                                                   float* __restrict__ stats_acc,
                                                   int* __restrict__ prog) {
  int tid = threadIdx.x;
  if (blockIdx.x == 0) {         // zero the 0xAA-poisoned accumulators/flags
    stats_acc[tid] = 0.f;        // 256 floats
    if (tid < 8) prog[tid] = 0;
  }
  int g = blockIdx.x * 256 + tid;              // 65536 = B*N
  int b = g >> 13, n = g & 8191;
  const float* xb = xyz + b * 3 * NN;
  float x = xb[n], y = xb[NN + n], z = xb[2 * NN + n];
  xyz4[g] = make_float4(x, y, z, fmaf(x, x, fmaf(y, y, z * z)));
  const float* pb = pts + b * 3 * NN;
  pts4[g] = make_float4(pb[n], pb[NN + n], pb[2 * NN + n], 0.f);
}

// ---------------- helpers ---------------------------------------------------
template <int CTRL>
__device__ __forceinline__ float dpp_max(float v) {
  int o = __builtin_amdgcn_update_dpp(__float_as_int(v), __float_as_int(v),
                                      CTRL, 0xf, 0xf, false);
  return fmaxf(v, __int_as_float(o));
}

__device__ __forceinline__ void insert32(float (&a)[32], float f) {
  // sorted ascending; keep 32 smallest. new[i] = min(a[i], max(a[i-1], f))
#pragma unroll
  for (int i = 31; i >= 1; --i) a[i] = fminf(a[i], fmaxf(a[i - 1], f));
  a[0] = fminf(a[0], f);
}

// ---------------- mega: fps (blocks 0..7) + knn/stats0 (blocks 8..263) ------
__global__ __launch_bounds__(512, 1) void mega_kernel(
    const float4* __restrict__ xyz4, const float4* __restrict__ pts4,
    float4* __restrict__ nxyz4, int* __restrict__ knn,
    const float* __restrict__ w0, float* __restrict__ stats_acc,
    int* __restrict__ prog, float* __restrict__ out_nxyz,
    float* __restrict__ out_fps) {
  __shared__ float lbuf[256][33];              // knn merge / stats combine; 33.8 KB
  __shared__ unsigned long long wslot[2][8];
  int tid = threadIdx.x;
  int lane = tid & 63, wid = tid >> 6;

  if (blockIdx.x < 8) {
    // =============== FPS role: one block per batch ===============
    int b = blockIdx.x;
    const float4* xb = xyz4 + b * NN;

    // thread owns contiguous points [tid*16, tid*16+16) in AGPRs
    float ax[16], ay[16], az[16], dist[16];
#pragma unroll
    for (int j = 0; j < 16; ++j) {
      float4 t = xb[(tid << 4) + j];
      asm volatile("v_accvgpr_write_b32 %0, %1" : "=a"(ax[j]) : "v"(t.x));
      asm volatile("v_accvgpr_write_b32 %0, %1" : "=a"(ay[j]) : "v"(t.y));
      asm volatile("v_accvgpr_write_b32 %0, %1" : "=a"(az[j]) : "v"(t.z));
      dist[j] = 1e10f;
    }
    float4 c0 = xb[0];
    float cx = c0.x, cy = c0.y, cz = c0.z;
    if (tid == 0) {
      nxyz4[b * NS] = c0;                      // c0.w = |p|^2 from prep
      out_nxyz[b * 3 * NS] = c0.x;
      out_nxyz[b * 3 * NS + NS] = c0.y;
      out_nxyz[b * 3 * NS + 2 * NS] = c0.z;
      out_fps[b * NS] = 0.f;
    }
    __syncthreads();

    for (int s = 1; s < NS; ++s) {
      // exact (no-FMA, left-to-right) distance + running min; argmax DEFERRED
#pragma unroll
      for (int j = 0; j < 16; ++j) {
        float x, y, z;
        asm volatile("v_accvgpr_read_b32 %0, %1" : "=v"(x) : "a"(ax[j]));
        asm volatile("v_accvgpr_read_b32 %0, %1" : "=v"(y) : "a"(ay[j]));
        asm volatile("v_accvgpr_read_b32 %0, %1" : "=v"(z) : "a"(az[j]));
        float dx = __fsub_rn(x, cx);
        float dy = __fsub_rn(y, cy);
        float dz = __fsub_rn(z, cz);
        float d = __fadd_rn(__fadd_rn(__fmul_rn(dx, dx), __fmul_rn(dy, dy)),
                            __fmul_rn(dz, dz));
        dist[j] = fminf(dist[j], d);
      }
      float lmax = dist[0];
#pragma unroll
      for (int j = 1; j < 16; ++j) lmax = fmaxf(lmax, dist[j]);  // reassoc tree

      // wave64 max via DPP; result in lane 63
      float m = lmax;
      m = dpp_max<0x111>(m);  // row_shr:1
      m = dpp_max<0x112>(m);  // row_shr:2
      m = dpp_max<0x114>(m);  // row_shr:4
      m = dpp_max<0x118>(m);  // row_shr:8
      m = dpp_max<0x142>(m);  // row_bcast:15
      m = dpp_max<0x143>(m);  // row_bcast:31
      float wmax = __int_as_float(__builtin_amdgcn_readlane(__float_as_int(m), 63));

      unsigned long long bl = __ballot(lmax == wmax);
      int l0 = __ffsll(bl) - 1;                // lowest lane = lowest gid
      int bj = 0;
      if (lmax == wmax) {                      // only matching lanes scan
#pragma unroll
        for (int t = 15; t >= 0; --t)
          if (dist[t] == lmax) bj = t;         // smallest j on ties
      }
      int gcand = (tid << 4) + bj;
      int gw = __builtin_amdgcn_readlane(gcand, l0);

      if (lane == 0)
        wslot[s & 1][wid] = (((unsigned long long)__float_as_uint(wmax)) << 32) |
                            (unsigned)(8191 - gw);  // u64-max => max val, min gid
      __syncthreads();

      unsigned long long vm = wslot[s & 1][0];
#pragma unroll
      for (int k = 1; k < 8; ++k) {
        unsigned long long o = wslot[s & 1][k];
        vm = o > vm ? o : vm;
      }
      int gid = 8191 - (int)(unsigned)(vm & 0xFFFFFFFFull);
      gid = __builtin_amdgcn_readfirstlane(gid);

      float4 c = xb[gid];                      // s_load, L2-resident broadcast
      cx = c.x; cy = c.y; cz = c.z;
      if (tid == 0) {
        nxyz4[b * NS + s] = c;
        out_nxyz[b * 3 * NS + s] = c.x;
        out_nxyz[b * 3 * NS + NS + s] = c.y;
        out_nxyz[b * 3 * NS + 2 * NS + s] = c.z;
        out_fps[b * NS + s] = (float)gid;
        if (((s + 1) & 63) == 0) {             // publish completed 64-query tile
          __threadfence();
          __hip_atomic_store(&prog[b], s + 1, __ATOMIC_RELEASE,
                             __HIP_MEMORY_SCOPE_AGENT);
        }
      }
      // single barrier/iter: parity buffer wslot[s&1]
    }
    return;
  }

  // =============== kNN + stage0-stats role: one block per (batch, tile) =====
  int idx = blockIdx.x - 8;
  int b = idx >> 5, tile = idx & 31;
  const float4* xb = xyz4 + b * NN;
  const float4* pb = pts4 + b * NN;

  // wait until this tile's 64 centroids exist
  if (tid == 0) {
    int need = (tile + 1) * 64;
    while (__hip_atomic_load(&prog[b], __ATOMIC_ACQUIRE,
                             __HIP_MEMORY_SCOPE_AGENT) < need)
      __builtin_amdgcn_s_sleep(64);
  }
  __syncthreads();

  float arr[32];
  if (tid < 256) {                             // knn: 64 queries x 4 ref-chunks
    int q = tid & 63, chunk = tid >> 6;
    float4 Q = nxyz4[b * NS + tile * 64 + q];
    float qq = Q.w;
    float mx = -2.f * Q.x, my = -2.f * Q.y, mz = -2.f * Q.z;
#pragma unroll
    for (int i = 0; i < 32; ++i) arr[i] = __uint_as_float(0x7f7fffffu);
    const float4* refs = xb + chunk * 2048;
    int rbase = chunk * 2048;
    for (int r = 0; r < 2048; r += 4) {
      float4 R0 = refs[r], R1 = refs[r + 1], R2 = refs[r + 2], R3 = refs[r + 3];
      float d0 = fmaxf(fmaf(R0.x, mx, fmaf(R0.y, my, fmaf(R0.z, mz, R0.w + qq))), 0.f);
      float d1 = fmaxf(fmaf(R1.x, mx, fmaf(R1.y, my, fmaf(R1.z, mz, R1.w + qq))), 0.f);
      float d2 = fmaxf(fmaf(R2.x, mx, fmaf(R2.y, my, fmaf(R2.z, mz, R2.w + qq))), 0.f);
      float d3 = fmaxf(fmaf(R3.x, mx, fmaf(R3.y, my, fmaf(R3.z, mz, R3.w + qq))), 0.f);
      float f0 = __uint_as_float((__float_as_uint(d0) & 0xFFFFE000u) | (unsigned)(rbase + r));
      float f1 = __uint_as_float((__float_as_uint(d1) & 0xFFFFE000u) | (unsigned)(rbase + r + 1));
      float f2 = __uint_as_float((__float_as_uint(d2) & 0xFFFFE000u) | (unsigned)(rbase + r + 2));
      float f3 = __uint_as_float((__float_as_uint(d3) & 0xFFFFE000u) | (unsigned)(rbase + r + 3));
      if (f0 < arr[31]) insert32(arr, f0);
      if (f1 < arr[31]) insert32(arr, f1);
      if (f2 < arr[31]) insert32(arr, f2);
      if (f3 < arr[31]) insert32(arr, f3);
    }
#pragma unroll
    for (int i = 0; i < 32; ++i) lbuf[tid][i] = arr[i];
  }
  __syncthreads();
  if (tid < 64) {                              // merge 4 chunks for query tid
    for (int c = 1; c < 4; ++c)
      for (int i = 0; i < 32; ++i) {
        float f = lbuf[c * 64 + tid][i];
        if (f < arr[31]) insert32(arr, f);
      }
    int base = (b * NS + tile * 64 + tid) * NK;
#pragma unroll
    for (int i = 0; i < 32; ++i) {
      knn[base + i] = (int)(__float_as_uint(arr[i]) & 0x1FFFu);
      lbuf[tid][i] = arr[i];                   // merged result for stats phase
    }
  }
  __syncthreads();

  // stage0 stats: y0 = W0 * [pos_diff, pts]; accumulate sum/sumsq per channel
  float sum[32], sumsq[32];
#pragma unroll
  for (int o = 0; o < 32; ++o) { sum[o] = 0.f; sumsq[o] = 0.f; }
  for (int t = 0; t < 4; ++t) {                // 2048 pairs / 512 threads
    int e = tid * 4 + t;
    int sq = e >> 5, k = e & 31;
    int nid = (int)(__float_as_uint(lbuf[sq][k]) & 0x1FFFu);
    float4 Q = nxyz4[b * NS + tile * 64 + sq];
    float4 R = xb[nid];
    float4 P = pb[nid];
    float x0[6] = {R.x - Q.x, R.y - Q.y, R.z - Q.z, P.x, P.y, P.z};
#pragma unroll
    for (int o = 0; o < 32; ++o) {
      float a = w0[o * 6] * x0[0];
#pragma unroll
      for (int c = 1; c < 6; ++c) a = fmaf(w0[o * 6 + c], x0[c], a);
      sum[o] += a;
      sumsq[o] = fmaf(a, a, sumsq[o]);
    }
  }
#pragma unroll
  for (int o = 0; o < 32; ++o) {               // wave reduce
    float s = sum[o], q = sumsq[o];
#pragma unroll
    for (int d = 1; d < 64; d <<= 1) { s += __shfl_xor(s, d); q += __shfl_xor(q, d); }
    sum[o] = s; sumsq[o] = q;
  }
  __syncthreads();                             // lbuf reads done; reuse as cmb
  float* cmb = &lbuf[0][0];                    // 8 waves x 64 floats
  if (lane == 0) {
#pragma unroll
    for (int o = 0; o < 32; ++o) {
      cmb[wid * 64 + o] = sum[o];
      cmb[wid * 64 + 32 + o] = sumsq[o];
    }
  }
  __syncthreads();
  if (tid < 64) {
    float tot = 0.f;
#pragma unroll
    for (int w = 0; w < 8; ++w) tot += cmb[w * 64 + tid];
    atomicAdd(&stats_acc[tid], tot);           // [0..31]=sum, [32..63]=sumsq
  }
}

// ---------------- MLP sweep passes (BN needs global stats) ------------------
// STAGE 1: ->y1 stats | 2: ->y2 stats | 3: full + maxK + out
template <int STAGE>
__global__ __launch_bounds__(256) void mlp_kernel(
    const float4* __restrict__ xyz4, const float4* __restrict__ pts4,
    const float4* __restrict__ nxyz4, const int* __restrict__ knn,
    const float* __restrict__ w0, const float* __restrict__ w1,
    const float* __restrict__ w2, const float* __restrict__ ab,
    float* __restrict__ acc, float* __restrict__ out_np) {
  constexpr int C = (STAGE == 2) ? 64 : 32;              // stats channels
  constexpr int SM = (STAGE == 3) ? 8 * 64 * 32 : 512;   // floats
  __shared__ float smem[SM];
  int blk = blockIdx.x;
  int b = blk >> 6, s0 = (blk & 63) * 32;
  int tid = threadIdx.x, sl = tid & 31, ksec = tid >> 5;
  int lane = tid & 63, wid = tid >> 6;
  int s = s0 + sl;
  float4 Q = nxyz4[b * NS + s];
  const float4* xb = xyz4 + b * NN;
  const float4* pb = pts4 + b * NN;
  const int* kb = knn + (b * NS + s) * NK + ksec * 4;

  float acc1[(STAGE == 3) ? 64 : C];
  float acc2[(STAGE == 3) ? 1 : C];
  if constexpr (STAGE == 3) {
#pragma unroll
    for (int o = 0; o < 64; ++o) acc1[o] = -3.4e38f;
  } else {
#pragma unroll
    for (int o = 0; o < C; ++o) { acc1[o] = 0.f; acc2[o] = 0.f; }
  }

  for (int kk = 0; kk < 4; ++kk) {
    int nid = kb[kk];
    float4 R = xb[nid];
    float4 P = pb[nid];
    float x0[6] = {R.x - Q.x, R.y - Q.y, R.z - Q.z, P.x, P.y, P.z};
    float h[32];
#pragma unroll
    for (int o = 0; o < 32; ++o) {
      float a = w0[o * 6] * x0[0];
#pragma unroll
      for (int c = 1; c < 6; ++c) a = fmaf(w0[o * 6 + c], x0[c], a);
      h[o] = fmaxf(fmaf(a, ab[o], ab[64 + o]), 0.f);
    }
    float h1[32];
#pragma unroll
    for (int o = 0; o < 32; ++o) {
      float a = 0.f;
#pragma unroll
      for (int i = 0; i < 32; ++i) a = fmaf(w1[o * 32 + i], h[i], a);
      h1[o] = a;
    }
    if constexpr (STAGE == 1) {
#pragma unroll
      for (int o = 0; o < 32; ++o) { acc1[o] += h1[o]; acc2[o] = fmaf(h1[o], h1[o], acc2[o]); }
    } else {
#pragma unroll
      for (int o = 0; o < 32; ++o) h1[o] = fmaxf(fmaf(h1[o], ab[128 + o], ab[192 + o]), 0.f);
#pragma unroll
      for (int o = 0; o < 64; ++o) {
        float a = 0.f;
#pragma unroll
        for (int i = 0; i < 32; ++i) a = fmaf(w2[o * 32 + i], h1[i], a);
        if constexpr (STAGE == 2) {
          acc1[o] += a;
          acc2[o] = fmaf(a, a, acc2[o]);
        } else {
          acc1[o] = fmaxf(acc1[o], fmaxf(fmaf(a, ab[256 + o], ab[320 + o]), 0.f));
        }
      }
    }
  }

  if constexpr (STAGE < 3) {
    // wave shuffle reduce -> per-wave slot -> per-block atomicAdd
#pragma unroll
    for (int o = 0; o < C; ++o) {
      float v1 = acc1[o], v2 = acc2[o];
#pragma unroll
      for (int d = 1; d < 64; d <<= 1) { v1 += __shfl_xor(v1, d); v2 += __shfl_xor(v2, d); }
      acc1[o] = v1; acc2[o] = v2;
    }
    if (lane == 0) {
#pragma unroll
      for (int o = 0; o < C; ++o) {
        smem[wid * 2 * C + o] = acc1[o];
        smem[wid * 2 * C + C + o] = acc2[o];
      }
    }
    __syncthreads();
    if (tid < 2 * C) {
      float v = smem[tid] + smem[2 * C + tid] + smem[4 * C + tid] + smem[6 * C + tid];
      atomicAdd(&acc[tid], v);
    }
  } else {
#pragma unroll
    for (int o = 0; o < 64; ++o) smem[ksec * 2048 + o * 32 + sl] = acc1[o];
    __syncthreads();
#pragma unroll
    for (int i = 0; i < 8; ++i) {
      int e = i * 256 + tid;
      int ch = e >> 5, ss = e & 31;
      float v = smem[ch * 32 + ss];
#pragma unroll
      for (int ks = 1; ks < 8; ++ks) v = fmaxf(v, smem[ks * 2048 + ch * 32 + ss]);
      out_np[b * 64 * NS + ch * NS + s0 + ss] = v;
    }
  }
}

__global__ __launch_bounds__(64) void finalize_kernel(const float* __restrict__ acc,
                                                      const float* __restrict__ g,
                                                      const float* __restrict__ bt,
                                                      float* __restrict__ ab, int C) {
  int tid = threadIdx.x;
  if (tid < C) {
    float s1 = acc[tid];
    float s2 = acc[C + tid];
    const float ninv = 1.0f / 524288.0f;  // B*S*K
    float mean = s1 * ninv;
    float var = s2 * ninv - mean * mean;
    float inv = 1.0f / sqrtf(var + 1e-5f);
    float a = g[tid] * inv;
    ab[tid] = a;
    ab[64 + tid] = bt[tid] - mean * a;
  }
}

// ---------------------------------------------------------------------------
extern "C" void kernel_launch(void* const* d_in, const int* in_sizes, int n_in,
                              void* d_out, int out_size, void* d_ws, size_t ws_size,
                              hipStream_t stream) {
  const float* xyz = (const float*)d_in[0];
  const float* pts = (const float*)d_in[1];
  const float* w0 = (const float*)d_in[2];
  const float* g0 = (const float*)d_in[3];
  const float* b0 = (const float*)d_in[4];
  const float* w1 = (const float*)d_in[5];
  const float* g1 = (const float*)d_in[6];
  const float* b1 = (const float*)d_in[7];
  const float* w2 = (const float*)d_in[8];
  const float* g2 = (const float*)d_in[9];
  const float* b2 = (const float*)d_in[10];
  float* out = (float*)d_out;
  float* ws = (float*)d_ws;

  float4* xyz4 = (float4*)ws;                  // 262144 floats
  float4* pts4 = (float4*)(ws + 262144);       // 262144
  float4* nxyz4 = (float4*)(ws + 524288);      // 65536
  int* knn = (int*)(ws + 589824);              // 524288 ints
  float* stats_acc = ws + 1114112;             // 256 floats (zeroed in prep)
  int* prog = (int*)(ws + 1114368);            // 8 ints (zeroed in prep)
  float* ab = ws + 1114432;                    // 384 floats
  float* out_np = out + 49152;                 // new_points [8,64,2048]
  float* out_fps = out + 1097728;              // fps_idx as float [8,2048]

  prep_kernel<<<256, 256, 0, stream>>>(xyz, pts, xyz4, pts4, stats_acc, prog);
  mega_kernel<<<264, 512, 0, stream>>>(xyz4, pts4, nxyz4, knn, w0, stats_acc,
                                       prog, out, out_fps);
  finalize_kernel<<<1, 64, 0, stream>>>(stats_acc, g0, b0, ab, 32);
  mlp_kernel<1><<<512, 256, 0, stream>>>(xyz4, pts4, nxyz4, knn, w0, w1, w2, ab,
                                         stats_acc + 64, nullptr);
  finalize_kernel<<<1, 64, 0, stream>>>(stats_acc + 64, g1, b1, ab + 128, 32);
  mlp_kernel<2><<<512, 256, 0, stream>>>(xyz4, pts4, nxyz4, knn, w0, w1, w2, ab,
                                         stats_acc + 128, nullptr);
  finalize_kernel<<<1, 64, 0, stream>>>(stats_acc + 128, g2, b2, ab + 256, 64);
  mlp_kernel<3><<<512, 256, 0, stream>>>(xyz4, pts4, nxyz4, knn, w0, w1, w2, ab,
                                         nullptr, out_np);
}

// Round 7
// 3240.706 us; speedup vs baseline: 1.2034x; 1.2034x over previous
//
#include <hip/hip_runtime.h>
#include <hip/hip_bf16.h>
#include <math.h>

// ---------------------------------------------------------------------------
// PointNet++ Set Abstraction: FPS -> kNN -> grouped MLP(6->32->32->64) with
// BatchNorm(training stats) + ReLU -> max over K.
// B=8, N=8192, S=2048, K=32. All fp32.
//
// R6 structure: mega-kernel, grid EXACTLY 256 (=CU count), 1 block/CU by LDS:
//   blocks 0..7   = FPS (one per batch); coords in AGPRs (dist loop) + LDS
//                   (centroid broadcast: kills the serial-dependent L2 load
//                   that R5's knn traffic was inflating).
//   blocks 8..255 = 248 kNN+stage0-stats workers; workers 0..7 take 2 tiles
//                   (earliest b0/t0-7 + last b7/t24-31). No CU ever hosts
//                   fps+knn together; no pending blocks => no deadlock.
//
// d_out layout (floats): new_xyz [8,3,2048] | new_points [8,64,2048] | fps_idx [8,2048]
// ---------------------------------------------------------------------------

#define NB 8
#define NN 8192
#define NS 2048
#define NK 32

// ---------------- prep: transpose to [B,N,4] with w = |p|^2 -----------------
__global__ __launch_bounds__(256) void prep_kernel(const float* __restrict__ xyz,
                                                   const float* __restrict__ pts,
                                                   float4* __restrict__ xyz4,
                                                   float4* __restrict__ pts4,
                                                   float* __restrict__ stats_acc,
                                                   int* __restrict__ prog) {
  int tid = threadIdx.x;
  if (blockIdx.x == 0) {         // zero the 0xAA-poisoned accumulators/flags
    stats_acc[tid] = 0.f;        // 256 floats
    if (tid < 8) prog[tid] = 0;
  }
  int g = blockIdx.x * 256 + tid;              // 65536 = B*N
  int b = g >> 13, n = g & 8191;
  const float* xb = xyz + b * 3 * NN;
  float x = xb[n], y = xb[NN + n], z = xb[2 * NN + n];
  xyz4[g] = make_float4(x, y, z, fmaf(x, x, fmaf(y, y, z * z)));
  const float* pb = pts + b * 3 * NN;
  pts4[g] = make_float4(pb[n], pb[NN + n], pb[2 * NN + n], 0.f);
}

// ---------------- helpers ---------------------------------------------------
template <int CTRL>
__device__ __forceinline__ float dpp_max(float v) {
  int o = __builtin_amdgcn_update_dpp(__float_as_int(v), __float_as_int(v),
                                      CTRL, 0xf, 0xf, false);
  return fmaxf(v, __int_as_float(o));
}

__device__ __forceinline__ void insert32(float (&a)[32], float f) {
  // sorted ascending; keep 32 smallest. new[i] = min(a[i], max(a[i-1], f))
#pragma unroll
  for (int i = 31; i >= 1; --i) a[i] = fminf(a[i], fmaxf(a[i - 1], f));
  a[0] = fminf(a[0], f);
}

// ---------------- mega: fps (0..7) + knn/stats0 workers (8..255) ------------
union MegaShm {
  struct {
    float lxyz[3 * NN];                        // 96 KB interleaved coords
    unsigned long long wslot[2][8];
  } f;                                         // fps role
  float lbuf[256][33];                         // knn role (33.8 KB, padded)
};

__global__ __launch_bounds__(512, 1) void mega_kernel(
    const float4* __restrict__ xyz4, const float4* __restrict__ pts4,
    float4* __restrict__ nxyz4, int* __restrict__ knn,
    const float* __restrict__ w0, float* __restrict__ stats_acc,
    int* __restrict__ prog, float* __restrict__ out_nxyz,
    float* __restrict__ out_fps) {
  __shared__ MegaShm sh;                       // 98.4 KB -> 1 block/CU
  int tid = threadIdx.x;
  int lane = tid & 63, wid = tid >> 6;

  if (blockIdx.x < 8) {
    // =============== FPS role: one block per batch ===============
    int b = blockIdx.x;
    const float4* xb = xyz4 + b * NN;

    // stage coords into LDS (for the per-iter centroid broadcast only)
    for (int i = tid; i < NN; i += 512) {
      float4 t = xb[i];
      sh.f.lxyz[3 * i] = t.x;
      sh.f.lxyz[3 * i + 1] = t.y;
      sh.f.lxyz[3 * i + 2] = t.z;
    }
    // thread owns contiguous points [tid*16, tid*16+16) in AGPRs (dist loop)
    float ax[16], ay[16], az[16], dist[16];
#pragma unroll
    for (int j = 0; j < 16; ++j) {
      float4 t = xb[(tid << 4) + j];
      asm volatile("v_accvgpr_write_b32 %0, %1" : "=a"(ax[j]) : "v"(t.x));
      asm volatile("v_accvgpr_write_b32 %0, %1" : "=a"(ay[j]) : "v"(t.y));
      asm volatile("v_accvgpr_write_b32 %0, %1" : "=a"(az[j]) : "v"(t.z));
      dist[j] = 1e10f;
    }
    float4 c0 = xb[0];
    float cx = c0.x, cy = c0.y, cz = c0.z;
    if (tid == 0) {
      nxyz4[b * NS] = c0;                      // c0.w = |p|^2 from prep
      out_nxyz[b * 3 * NS] = c0.x;
      out_nxyz[b * 3 * NS + NS] = c0.y;
      out_nxyz[b * 3 * NS + 2 * NS] = c0.z;
      out_fps[b * NS] = 0.f;
    }
    __syncthreads();

    for (int s = 1; s < NS; ++s) {
      // exact (no-FMA, left-to-right) distance + running min; argmax deferred
#pragma unroll
      for (int j = 0; j < 16; ++j) {
        float x, y, z;
        asm volatile("v_accvgpr_read_b32 %0, %1" : "=v"(x) : "a"(ax[j]));
        asm volatile("v_accvgpr_read_b32 %0, %1" : "=v"(y) : "a"(ay[j]));
        asm volatile("v_accvgpr_read_b32 %0, %1" : "=v"(z) : "a"(az[j]));
        float dx = __fsub_rn(x, cx);
        float dy = __fsub_rn(y, cy);
        float dz = __fsub_rn(z, cz);
        float d = __fadd_rn(__fadd_rn(__fmul_rn(dx, dx), __fmul_rn(dy, dy)),
                            __fmul_rn(dz, dz));
        dist[j] = fminf(dist[j], d);
      }
      float lmax = dist[0];
#pragma unroll
      for (int j = 1; j < 16; ++j) lmax = fmaxf(lmax, dist[j]);

      // wave64 max via DPP; result in lane 63
      float m = lmax;
      m = dpp_max<0x111>(m);  // row_shr:1
      m = dpp_max<0x112>(m);  // row_shr:2
      m = dpp_max<0x114>(m);  // row_shr:4
      m = dpp_max<0x118>(m);  // row_shr:8
      m = dpp_max<0x142>(m);  // row_bcast:15
      m = dpp_max<0x143>(m);  // row_bcast:31
      float wmax = __int_as_float(__builtin_amdgcn_readlane(__float_as_int(m), 63));

      unsigned long long bl = __ballot(lmax == wmax);
      int l0 = __ffsll(bl) - 1;                // lowest lane = lowest gid
      int bj = 0;
      if (lmax == wmax) {                      // only matching lanes scan
#pragma unroll
        for (int t = 15; t >= 0; --t)
          if (dist[t] == lmax) bj = t;         // smallest j on ties
      }
      int gcand = (tid << 4) + bj;
      int gw = __builtin_amdgcn_readlane(gcand, l0);

      if (lane == 0)
        sh.f.wslot[s & 1][wid] =
            (((unsigned long long)__float_as_uint(wmax)) << 32) |
            (unsigned)(8191 - gw);             // u64-max => max val, min gid
      __syncthreads();

      unsigned long long vm = sh.f.wslot[s & 1][0];
#pragma unroll
      for (int k = 1; k < 8; ++k) {
        unsigned long long o = sh.f.wslot[s & 1][k];
        vm = o > vm ? o : vm;
      }
      int gid = 8191 - (int)(unsigned)(vm & 0xFFFFFFFFull);
      gid = __builtin_amdgcn_readfirstlane(gid);

      // centroid from LDS broadcast: NO global load on the serial path
      cx = sh.f.lxyz[3 * gid];
      cy = sh.f.lxyz[3 * gid + 1];
      cz = sh.f.lxyz[3 * gid + 2];
      if (tid == 0) {
        float w = fmaf(cx, cx, fmaf(cy, cy, cz * cz));  // == prep formula
        nxyz4[b * NS + s] = make_float4(cx, cy, cz, w);
        out_nxyz[b * 3 * NS + s] = cx;
        out_nxyz[b * 3 * NS + NS + s] = cy;
        out_nxyz[b * 3 * NS + 2 * NS + s] = cz;
        out_fps[b * NS + s] = (float)gid;
        if (((s + 1) & 63) == 0) {             // publish completed 64-query tile
          __threadfence();
          __hip_atomic_store(&prog[b], s + 1, __ATOMIC_RELEASE,
                             __HIP_MEMORY_SCOPE_AGENT);
        }
      }
      // single barrier/iter: parity buffer wslot[s&1]
    }
    return;
  }

  // =============== kNN + stage0-stats role ===============
  // worker w in [0,248): tile w; workers 0..7 also take tile 248+w.
  int w = blockIdx.x - 8;
  for (int ti = 0; ti < 2; ++ti) {
    if (ti == 1 && w >= 8) break;
    int tile_id = (ti == 0) ? w : 248 + w;
    int b = tile_id >> 5, tile = tile_id & 31;
    const float4* xb = xyz4 + b * NN;
    const float4* pb = pts4 + b * NN;

    if (tid == 0) {
      int need = (tile + 1) * 64;
      while (__hip_atomic_load(&prog[b], __ATOMIC_ACQUIRE,
                               __HIP_MEMORY_SCOPE_AGENT) < need)
        __builtin_amdgcn_s_sleep(64);
    }
    __syncthreads();

    float arr[32];
    if (tid < 256) {                           // knn: 64 queries x 4 ref-chunks
      int q = tid & 63, chunk = tid >> 6;
      float4 Q = nxyz4[b * NS + tile * 64 + q];
      float qq = Q.w;
      float mx = -2.f * Q.x, my = -2.f * Q.y, mz = -2.f * Q.z;
#pragma unroll
      for (int i = 0; i < 32; ++i) arr[i] = __uint_as_float(0x7f7fffffu);
      const float4* refs = xb + chunk * 2048;
      int rbase = chunk * 2048;
      for (int r = 0; r < 2048; r += 4) {
        float4 R0 = refs[r], R1 = refs[r + 1], R2 = refs[r + 2], R3 = refs[r + 3];
        float d0 = fmaxf(fmaf(R0.x, mx, fmaf(R0.y, my, fmaf(R0.z, mz, R0.w + qq))), 0.f);
        float d1 = fmaxf(fmaf(R1.x, mx, fmaf(R1.y, my, fmaf(R1.z, mz, R1.w + qq))), 0.f);
        float d2 = fmaxf(fmaf(R2.x, mx, fmaf(R2.y, my, fmaf(R2.z, mz, R2.w + qq))), 0.f);
        float d3 = fmaxf(fmaf(R3.x, mx, fmaf(R3.y, my, fmaf(R3.z, mz, R3.w + qq))), 0.f);
        float f0 = __uint_as_float((__float_as_uint(d0) & 0xFFFFE000u) | (unsigned)(rbase + r));
        float f1 = __uint_as_float((__float_as_uint(d1) & 0xFFFFE000u) | (unsigned)(rbase + r + 1));
        float f2 = __uint_as_float((__float_as_uint(d2) & 0xFFFFE000u) | (unsigned)(rbase + r + 2));
        float f3 = __uint_as_float((__float_as_uint(d3) & 0xFFFFE000u) | (unsigned)(rbase + r + 3));
        if (f0 < arr[31]) insert32(arr, f0);
        if (f1 < arr[31]) insert32(arr, f1);
        if (f2 < arr[31]) insert32(arr, f2);
        if (f3 < arr[31]) insert32(arr, f3);
      }
#pragma unroll
      for (int i = 0; i < 32; ++i) sh.lbuf[tid][i] = arr[i];
    }
    __syncthreads();
    if (tid < 64) {                            // merge 4 chunks for query tid
      for (int c = 1; c < 4; ++c)
        for (int i = 0; i < 32; ++i) {
          float f = sh.lbuf[c * 64 + tid][i];
          if (f < arr[31]) insert32(arr, f);
        }
      int base = (b * NS + tile * 64 + tid) * NK;
#pragma unroll
      for (int i = 0; i < 32; ++i) {
        knn[base + i] = (int)(__float_as_uint(arr[i]) & 0x1FFFu);
        sh.lbuf[tid][i] = arr[i];              // merged result for stats phase
      }
    }
    __syncthreads();

    // stage0 stats: y0 = W0 * [pos_diff, pts]; per-channel sum/sumsq
    float sum[32], sumsq[32];
#pragma unroll
    for (int o = 0; o < 32; ++o) { sum[o] = 0.f; sumsq[o] = 0.f; }
    for (int t = 0; t < 4; ++t) {              // 2048 pairs / 512 threads
      int e = tid * 4 + t;
      int sq = e >> 5, k = e & 31;
      int nid = (int)(__float_as_uint(sh.lbuf[sq][k]) & 0x1FFFu);
      float4 Q = nxyz4[b * NS + tile * 64 + sq];
      float4 R = xb[nid];
      float4 P = pb[nid];
      float x0[6] = {R.x - Q.x, R.y - Q.y, R.z - Q.z, P.x, P.y, P.z};
#pragma unroll
      for (int o = 0; o < 32; ++o) {
        float a = w0[o * 6] * x0[0];
#pragma unroll
        for (int c = 1; c < 6; ++c) a = fmaf(w0[o * 6 + c], x0[c], a);
        sum[o] += a;
        sumsq[o] = fmaf(a, a, sumsq[o]);
      }
    }
#pragma unroll
    for (int o = 0; o < 32; ++o) {             // wave reduce
      float s = sum[o], q = sumsq[o];
#pragma unroll
      for (int d = 1; d < 64; d <<= 1) { s += __shfl_xor(s, d); q += __shfl_xor(q, d); }
      sum[o] = s; sumsq[o] = q;
    }
    __syncthreads();                           // lbuf reads done; reuse as cmb
    float* cmb = &sh.lbuf[0][0];               // 8 waves x 64 floats
    if (lane == 0) {
#pragma unroll
      for (int o = 0; o < 32; ++o) {
        cmb[wid * 64 + o] = sum[o];
        cmb[wid * 64 + 32 + o] = sumsq[o];
      }
    }
    __syncthreads();
    if (tid < 64) {
      float tot = 0.f;
#pragma unroll
      for (int wv = 0; wv < 8; ++wv) tot += cmb[wv * 64 + tid];
      atomicAdd(&stats_acc[tid], tot);         // [0..31]=sum, [32..63]=sumsq
    }
    __syncthreads();                           // lbuf safe for next tile
  }
}

// ---------------- MLP sweep passes (BN needs global stats) ------------------
// STAGE 1: ->y1 stats | 2: ->y2 stats | 3: full + maxK + out
template <int STAGE>
__global__ __launch_bounds__(256) void mlp_kernel(
    const float4* __restrict__ xyz4, const float4* __restrict__ pts4,
    const float4* __restrict__ nxyz4, const int* __restrict__ knn,
    const float* __restrict__ w0, const float* __restrict__ w1,
    const float* __restrict__ w2, const float* __restrict__ ab,
    float* __restrict__ acc, float* __restrict__ out_np) {
  constexpr int C = (STAGE == 2) ? 64 : 32;              // stats channels
  constexpr int SM = (STAGE == 3) ? 8 * 64 * 32 : 512;   // floats
  __shared__ float smem[SM];
  int blk = blockIdx.x;
  int b = blk >> 6, s0 = (blk & 63) * 32;
  int tid = threadIdx.x, sl = tid & 31, ksec = tid >> 5;
  int lane = tid & 63, wid = tid >> 6;
  int s = s0 + sl;
  float4 Q = nxyz4[b * NS + s];
  const float4* xb = xyz4 + b * NN;
  const float4* pb = pts4 + b * NN;
  const int* kb = knn + (b * NS + s) * NK + ksec * 4;

  float acc1[(STAGE == 3) ? 64 : C];
  float acc2[(STAGE == 3) ? 1 : C];
  if constexpr (STAGE == 3) {
#pragma unroll
    for (int o = 0; o < 64; ++o) acc1[o] = -3.4e38f;
  } else {
#pragma unroll
    for (int o = 0; o < C; ++o) { acc1[o] = 0.f; acc2[o] = 0.f; }
  }

  for (int kk = 0; kk < 4; ++kk) {
    int nid = kb[kk];
    float4 R = xb[nid];
    float4 P = pb[nid];
    float x0[6] = {R.x - Q.x, R.y - Q.y, R.z - Q.z, P.x, P.y, P.z};
    float h[32];
#pragma unroll
    for (int o = 0; o < 32; ++o) {
      float a = w0[o * 6] * x0[0];
#pragma unroll
      for (int c = 1; c < 6; ++c) a = fmaf(w0[o * 6 + c], x0[c], a);
      h[o] = fmaxf(fmaf(a, ab[o], ab[64 + o]), 0.f);
    }
    float h1[32];
#pragma unroll
    for (int o = 0; o < 32; ++o) {
      float a = 0.f;
#pragma unroll
      for (int i = 0; i < 32; ++i) a = fmaf(w1[o * 32 + i], h[i], a);
      h1[o] = a;
    }
    if constexpr (STAGE == 1) {
#pragma unroll
      for (int o = 0; o < 32; ++o) { acc1[o] += h1[o]; acc2[o] = fmaf(h1[o], h1[o], acc2[o]); }
    } else {
#pragma unroll
      for (int o = 0; o < 32; ++o) h1[o] = fmaxf(fmaf(h1[o], ab[128 + o], ab[192 + o]), 0.f);
#pragma unroll
      for (int o = 0; o < 64; ++o) {
        float a = 0.f;
#pragma unroll
        for (int i = 0; i < 32; ++i) a = fmaf(w2[o * 32 + i], h1[i], a);
        if constexpr (STAGE == 2) {
          acc1[o] += a;
          acc2[o] = fmaf(a, a, acc2[o]);
        } else {
          acc1[o] = fmaxf(acc1[o], fmaxf(fmaf(a, ab[256 + o], ab[320 + o]), 0.f));
        }
      }
    }
  }

  if constexpr (STAGE < 3) {
    // wave shuffle reduce -> per-wave slot -> per-block atomicAdd
#pragma unroll
    for (int o = 0; o < C; ++o) {
      float v1 = acc1[o], v2 = acc2[o];
#pragma unroll
      for (int d = 1; d < 64; d <<= 1) { v1 += __shfl_xor(v1, d); v2 += __shfl_xor(v2, d); }
      acc1[o] = v1; acc2[o] = v2;
    }
    if (lane == 0) {
#pragma unroll
      for (int o = 0; o < C; ++o) {
        smem[wid * 2 * C + o] = acc1[o];
        smem[wid * 2 * C + C + o] = acc2[o];
      }
    }
    __syncthreads();
    if (tid < 2 * C) {
      float v = smem[tid] + smem[2 * C + tid] + smem[4 * C + tid] + smem[6 * C + tid];
      atomicAdd(&acc[tid], v);
    }
  } else {
#pragma unroll
    for (int o = 0; o < 64; ++o) smem[ksec * 2048 + o * 32 + sl] = acc1[o];
    __syncthreads();
#pragma unroll
    for (int i = 0; i < 8; ++i) {
      int e = i * 256 + tid;
      int ch = e >> 5, ss = e & 31;
      float v = smem[ch * 32 + ss];
#pragma unroll
      for (int ks = 1; ks < 8; ++ks) v = fmaxf(v, smem[ks * 2048 + ch * 32 + ss]);
      out_np[b * 64 * NS + ch * NS + s0 + ss] = v;
    }
  }
}

__global__ __launch_bounds__(64) void finalize_kernel(const float* __restrict__ acc,
                                                      const float* __restrict__ g,
                                                      const float* __restrict__ bt,
                                                      float* __restrict__ ab, int C) {
  int tid = threadIdx.x;
  if (tid < C) {
    float s1 = acc[tid];
    float s2 = acc[C + tid];
    const float ninv = 1.0f / 524288.0f;  // B*S*K
    float mean = s1 * ninv;
    float var = s2 * ninv - mean * mean;
    float inv = 1.0f / sqrtf(var + 1e-5f);
    float a = g[tid] * inv;
    ab[tid] = a;
    ab[64 + tid] = bt[tid] - mean * a;
  }
}

// ---------------------------------------------------------------------------
extern "C" void kernel_launch(void* const* d_in, const int* in_sizes, int n_in,
                              void* d_out, int out_size, void* d_ws, size_t ws_size,
                              hipStream_t stream) {
  const float* xyz = (const float*)d_in[0];
  const float* pts = (const float*)d_in[1];
  const float* w0 = (const float*)d_in[2];
  const float* g0 = (const float*)d_in[3];
  const float* b0 = (const float*)d_in[4];
  const float* w1 = (const float*)d_in[5];
  const float* g1 = (const float*)d_in[6];
  const float* b1 = (const float*)d_in[7];
  const float* w2 = (const float*)d_in[8];
  const float* g2 = (const float*)d_in[9];
  const float* b2 = (const float*)d_in[10];
  float* out = (float*)d_out;
  float* ws = (float*)d_ws;

  float4* xyz4 = (float4*)ws;                  // 262144 floats
  float4* pts4 = (float4*)(ws + 262144);       // 262144
  float4* nxyz4 = (float4*)(ws + 524288);      // 65536
  int* knn = (int*)(ws + 589824);              // 524288 ints
  float* stats_acc = ws + 1114112;             // 256 floats (zeroed in prep)
  int* prog = (int*)(ws + 1114368);            // 8 ints (zeroed in prep)
  float* ab = ws + 1114432;                    // 384 floats
  float* out_np = out + 49152;                 // new_points [8,64,2048]
  float* out_fps = out + 1097728;              // fps_idx as float [8,2048]

  prep_kernel<<<256, 256, 0, stream>>>(xyz, pts, xyz4, pts4, stats_acc, prog);
  mega_kernel<<<256, 512, 0, stream>>>(xyz4, pts4, nxyz4, knn, w0, stats_acc,
                                       prog, out, out_fps);
  finalize_kernel<<<1, 64, 0, stream>>>(stats_acc, g0, b0, ab, 32);
  mlp_kernel<1><<<512, 256, 0, stream>>>(xyz4, pts4, nxyz4, knn, w0, w1, w2, ab,
                                         stats_acc + 64, nullptr);
  finalize_kernel<<<1, 64, 0, stream>>>(stats_acc + 64, g1, b1, ab + 128, 32);
  mlp_kernel<2><<<512, 256, 0, stream>>>(xyz4, pts4, nxyz4, knn, w0, w1, w2, ab,
                                         stats_acc + 128, nullptr);
  finalize_kernel<<<1, 64, 0, stream>>>(stats_acc + 128, g2, b2, ab + 256, 64);
  mlp_kernel<3><<<512, 256, 0, stream>>>(xyz4, pts4, nxyz4, knn, w0, w1, w2, ab,
                                         nullptr, out_np);
}